// Round 1
// baseline (761.662 us; speedup 1.0000x reference)
//
#include <hip/hip_runtime.h>
#include <stdint.h>

#define N 8192
#define D 256

typedef __attribute__((ext_vector_type(4))) float f32x4;
typedef __attribute__((ext_vector_type(8))) short bf16x8;

__device__ __forceinline__ unsigned short f2bf(float f) {
    unsigned u = __float_as_uint(f);
    u += 0x7fff + ((u >> 16) & 1);           // RNE
    return (unsigned short)(u >> 16);
}
__device__ __forceinline__ float leaky(float x) {
    return fmaxf(x, 0.f) + 0.2f * fminf(x, 0.f);
}

// ---------------- K1: Wh = x @ W (fp32), also write WhT bf16 [D][N] ----------------
#define K1_BM 16
__global__ __launch_bounds__(256) void k1_gemm(const float* __restrict__ x,
                                               const float* __restrict__ W,
                                               float* __restrict__ Wh,
                                               unsigned short* __restrict__ WhT) {
    __shared__ float xsT[32][20];   // [k][r], stride 20 floats (80B, 16B-aligned rows)
    const int t = threadIdx.x;      // = output column
    const int r0 = blockIdx.x * K1_BM;
    float acc[K1_BM];
#pragma unroll
    for (int i = 0; i < K1_BM; ++i) acc[i] = 0.f;

    for (int k0 = 0; k0 < D; k0 += 32) {
        __syncthreads();
        if (t < 128) {
            int r = t >> 3, ks = (t & 7) * 4;
            float4 v = *(const float4*)(x + (size_t)(r0 + r) * D + k0 + ks);
            xsT[ks + 0][r] = v.x; xsT[ks + 1][r] = v.y;
            xsT[ks + 2][r] = v.z; xsT[ks + 3][r] = v.w;
        }
        __syncthreads();
#pragma unroll 8
        for (int kk = 0; kk < 32; ++kk) {
            float wv = W[(size_t)(k0 + kk) * D + t];
#pragma unroll
            for (int rc = 0; rc < K1_BM / 4; ++rc) {
                float4 xv = *(const float4*)&xsT[kk][rc * 4];
                acc[rc * 4 + 0] += xv.x * wv;
                acc[rc * 4 + 1] += xv.y * wv;
                acc[rc * 4 + 2] += xv.z * wv;
                acc[rc * 4 + 3] += xv.w * wv;
            }
        }
    }
    // Wh fp32, row-major, coalesced per r
#pragma unroll
    for (int r = 0; r < K1_BM; ++r) Wh[(size_t)(r0 + r) * D + t] = acc[r];
    // WhT bf16 [D][N]: thread t owns column t -> contiguous 16 bf16 per block
    unsigned short pk[K1_BM];
#pragma unroll
    for (int r = 0; r < K1_BM; ++r) pk[r] = f2bf(acc[r]);
    uint4* dst = (uint4*)(WhT + (size_t)t * N + r0);
    dst[0] = *(uint4*)&pk[0];
    dst[1] = *(uint4*)&pk[8];
}

// ---------------- K2: e_src / e_dst (wave per row) ----------------
__global__ __launch_bounds__(256) void k2_edot(const float* __restrict__ Wh,
                                               const float* __restrict__ a,
                                               float* __restrict__ e_src,
                                               float* __restrict__ e_dst) {
    const int wave = threadIdx.x >> 6, lane = threadIdx.x & 63;
    const int row = blockIdx.x * 4 + wave;
    float4 wv = *(const float4*)(Wh + (size_t)row * D + lane * 4);
    float4 as = *(const float4*)(a + lane * 4);
    float4 ad = *(const float4*)(a + D + lane * 4);
    float ps = wv.x * as.x + wv.y * as.y + wv.z * as.z + wv.w * as.w;
    float pd = wv.x * ad.x + wv.y * ad.y + wv.z * ad.z + wv.w * ad.w;
#pragma unroll
    for (int m = 1; m < 64; m <<= 1) {
        ps += __shfl_xor(ps, m);
        pd += __shfl_xor(pd, m);
    }
    if (lane == 0) { e_src[row] = ps; e_dst[row] = pd; }
}

// ---------------- K3: maxdst = max(e_dst) ----------------
__global__ __launch_bounds__(256) void k3_max(const float* __restrict__ e_dst,
                                              float* __restrict__ maxdst) {
    __shared__ float red[4];
    const int t = threadIdx.x;
    float m = -3.4e38f;
    for (int i = t; i < N; i += 256) m = fmaxf(m, e_dst[i]);
#pragma unroll
    for (int msk = 1; msk < 64; msk <<= 1) m = fmaxf(m, __shfl_xor(m, msk));
    if ((t & 63) == 0) red[t >> 6] = m;
    __syncthreads();
    if (t == 0) *maxdst = fmaxf(fmaxf(red[0], red[1]), fmaxf(red[2], red[3]));
}

// ---------------- K4: masked softmax + PV matmul (flash-style, fixed m) ----------------
#define BM 32
#define BK 64
#define LDS_STRIDE 72   // ushorts; 144B rows: 16B-aligned, 2-way-max bank alias
__global__ __launch_bounds__(512) void k4_main(const float* __restrict__ adj,
                                               const unsigned short* __restrict__ WhT,
                                               const float* __restrict__ e_src,
                                               const float* __restrict__ e_dst,
                                               const float* __restrict__ maxdst,
                                               float* __restrict__ out) {
    __shared__ unsigned short p_lds[BM][LDS_STRIDE];   // P tile bf16 [32][64]
    __shared__ unsigned short wt_lds[D][LDS_STRIDE];   // WhT tile bf16 [256 n][64 k]
    __shared__ float es_lds[BM], m_lds[BM], l_lds[BM];

    const int t = threadIdx.x;
    const int r0 = blockIdx.x * BM;
    // P-generation coords: one row per thread, 4 cols
    const int pr = t >> 4;            // 0..31
    const int pc = (t & 15) * 4;      // 0..60
    const int gr = r0 + pr;
    // WhT staging coords: 2 threads per n-row, 32 k each (64B contiguous per thread)
    const int wn = t >> 1;            // 0..255
    const int wc = (t & 1) * 32;

    const int w = t >> 6;             // wave 0..7 -> cols w*32..w*32+31
    const int lane = t & 63;
    const int quad = lane >> 4, lo = lane & 15;

    const float md = *maxdst;
    if (t < BM) {
        float es = e_src[r0 + t];
        es_lds[t] = es;
        m_lds[t] = leaky(es + md);
    }

    f32x4 acc[2][2];
#pragma unroll
    for (int mt = 0; mt < 2; ++mt)
#pragma unroll
        for (int nt = 0; nt < 2; ++nt)
            acc[mt][nt] = (f32x4){0.f, 0.f, 0.f, 0.f};

    float lsum = 0.f;

    // prefetch registers for tile 0
    const float* adj_row = adj + (size_t)gr * N + pc;
    const unsigned short* wt_row = WhT + (size_t)wn * N + wc;
    float4 adjv = *(const float4*)(adj_row);
    float4 edv = *(const float4*)(e_dst + pc);
    uint4 wtv[4];
#pragma unroll
    for (int j = 0; j < 4; ++j) wtv[j] = *(const uint4*)(wt_row + j * 8);

    __syncthreads();   // es/m ready
    const float es = es_lds[pr];
    const float m = m_lds[pr];

    const int NIT = N / BK;
    for (int it = 0; it < NIT; ++it) {
        // ---- stage phase: compute P from prefetched regs, write LDS ----
        const int jbase = it * BK + pc;
        float av[4] = {adjv.x, adjv.y, adjv.z, adjv.w};
        float ev[4] = {edv.x, edv.y, edv.z, edv.w};
        unsigned short pk[4];
#pragma unroll
        for (int jj = 0; jj < 4; ++jj) {
            float e = leaky(es + ev[jj]);
            bool keep = (av[jj] > 0.f) || (jbase + jj == gr);
            float p = keep ? __expf(e - m) : 0.f;
            lsum += p;
            pk[jj] = f2bf(p);
        }
        *(ushort4*)&p_lds[pr][pc] = *(ushort4*)pk;
#pragma unroll
        for (int j = 0; j < 4; ++j) *(uint4*)&wt_lds[wn][wc + j * 8] = wtv[j];

        // ---- issue next tile's global loads (overlap with MFMA phase) ----
        if (it + 1 < NIT) {
            const int k0 = (it + 1) * BK;
            adjv = *(const float4*)(adj_row + k0);
            edv = *(const float4*)(e_dst + k0 + pc);
#pragma unroll
            for (int j = 0; j < 4; ++j) wtv[j] = *(const uint4*)(wt_row + k0 + j * 8);
        }
        __syncthreads();   // LDS tile ready

        // ---- MFMA phase ----
#pragma unroll
        for (int ks = 0; ks < BK; ks += 32) {
            bf16x8 afr[2];
#pragma unroll
            for (int mt = 0; mt < 2; ++mt)
                afr[mt] = *(const bf16x8*)&p_lds[mt * 16 + lo][ks + quad * 8];
#pragma unroll
            for (int nt = 0; nt < 2; ++nt) {
                bf16x8 bfr = *(const bf16x8*)&wt_lds[w * 32 + nt * 16 + lo][ks + quad * 8];
#pragma unroll
                for (int mt = 0; mt < 2; ++mt)
                    acc[mt][nt] = __builtin_amdgcn_mfma_f32_16x16x32_bf16(
                        afr[mt], bfr, acc[mt][nt], 0, 0, 0);
            }
        }
        __syncthreads();   // protect LDS before next stage phase
    }

    // ---- epilogue: reduce row sums l, write h = O / l ----
#pragma unroll
    for (int msk = 1; msk < 16; msk <<= 1) lsum += __shfl_xor(lsum, msk);
    if ((t & 15) == 0) l_lds[pr] = lsum;
    __syncthreads();

#pragma unroll
    for (int mt = 0; mt < 2; ++mt) {
#pragma unroll
        for (int nt = 0; nt < 2; ++nt) {
            f32x4 v = acc[mt][nt];
            int col = w * 32 + nt * 16 + lo;
#pragma unroll
            for (int reg = 0; reg < 4; ++reg) {
                int row = mt * 16 + quad * 4 + reg;
                out[(size_t)(r0 + row) * D + col] = v[reg] / l_lds[row];
            }
        }
    }
}

// ---------------- launch ----------------
extern "C" void kernel_launch(void* const* d_in, const int* in_sizes, int n_in,
                              void* d_out, int out_size, void* d_ws, size_t ws_size,
                              hipStream_t stream) {
    const float* x   = (const float*)d_in[0];   // [N, D]
    const float* adj = (const float*)d_in[1];   // [N, N]
    const float* W   = (const float*)d_in[2];   // [D, D]
    const float* a   = (const float*)d_in[3];   // [2*D]
    float* out = (float*)d_out;

    char* ws = (char*)d_ws;
    float* Wh            = (float*)(ws);                         // 8 MB
    unsigned short* WhT  = (unsigned short*)(ws + 8388608);      // 4 MB
    float* e_src         = (float*)(ws + 12582912);              // 32 KB
    float* e_dst         = (float*)(ws + 12615680);              // 32 KB
    float* maxdst        = (float*)(ws + 12648448);              // 4 B

    k1_gemm<<<N / K1_BM, 256, 0, stream>>>(x, W, Wh, WhT);
    k2_edot<<<N / 4, 256, 0, stream>>>(Wh, a, e_src, e_dst);
    k3_max<<<1, 256, 0, stream>>>(e_dst, maxdst);
    k4_main<<<N / BM, 512, 0, stream>>>(adj, WhT, e_src, e_dst, maxdst, out);
}

// Round 2
// 622.243 us; speedup vs baseline: 1.2241x; 1.2241x over previous
//
#include <hip/hip_runtime.h>
#include <stdint.h>

#define N 8192
#define D 256

typedef __attribute__((ext_vector_type(4))) float f32x4;
typedef __attribute__((ext_vector_type(8))) short bf16x8;

__device__ __forceinline__ unsigned short f2bf(float f) {
    unsigned u = __float_as_uint(f);
    u += 0x7fff + ((u >> 16) & 1);           // RNE
    return (unsigned short)(u >> 16);
}
__device__ __forceinline__ float leaky(float x) {
    return fmaxf(x, 0.f) + 0.2f * fminf(x, 0.f);
}

// ---------------- K1: Wh = x @ W (fp32), also write WhT bf16 [D][N] ----------------
#define K1_BM 16
__global__ __launch_bounds__(256) void k1_gemm(const float* __restrict__ x,
                                               const float* __restrict__ W,
                                               float* __restrict__ Wh,
                                               unsigned short* __restrict__ WhT) {
    __shared__ float xsT[32][20];   // [k][r]
    const int t = threadIdx.x;      // = output column
    const int r0 = blockIdx.x * K1_BM;
    float acc[K1_BM];
#pragma unroll
    for (int i = 0; i < K1_BM; ++i) acc[i] = 0.f;

    for (int k0 = 0; k0 < D; k0 += 32) {
        __syncthreads();
        if (t < 128) {
            int r = t >> 3, ks = (t & 7) * 4;
            float4 v = *(const float4*)(x + (size_t)(r0 + r) * D + k0 + ks);
            xsT[ks + 0][r] = v.x; xsT[ks + 1][r] = v.y;
            xsT[ks + 2][r] = v.z; xsT[ks + 3][r] = v.w;
        }
        __syncthreads();
#pragma unroll 8
        for (int kk = 0; kk < 32; ++kk) {
            float wv = W[(size_t)(k0 + kk) * D + t];
#pragma unroll
            for (int rc = 0; rc < K1_BM / 4; ++rc) {
                float4 xv = *(const float4*)&xsT[kk][rc * 4];
                acc[rc * 4 + 0] += xv.x * wv;
                acc[rc * 4 + 1] += xv.y * wv;
                acc[rc * 4 + 2] += xv.z * wv;
                acc[rc * 4 + 3] += xv.w * wv;
            }
        }
    }
#pragma unroll
    for (int r = 0; r < K1_BM; ++r) Wh[(size_t)(r0 + r) * D + t] = acc[r];
    unsigned short pk[K1_BM];
#pragma unroll
    for (int r = 0; r < K1_BM; ++r) pk[r] = f2bf(acc[r]);
    uint4* dst = (uint4*)(WhT + (size_t)t * N + r0);
    dst[0] = *(uint4*)&pk[0];
    dst[1] = *(uint4*)&pk[8];
}

// ---------------- K2: e_src / e_dst (wave per row) ----------------
__global__ __launch_bounds__(256) void k2_edot(const float* __restrict__ Wh,
                                               const float* __restrict__ a,
                                               float* __restrict__ e_src,
                                               float* __restrict__ e_dst) {
    const int wave = threadIdx.x >> 6, lane = threadIdx.x & 63;
    const int row = blockIdx.x * 4 + wave;
    float4 wv = *(const float4*)(Wh + (size_t)row * D + lane * 4);
    float4 as = *(const float4*)(a + lane * 4);
    float4 ad = *(const float4*)(a + D + lane * 4);
    float ps = wv.x * as.x + wv.y * as.y + wv.z * as.z + wv.w * as.w;
    float pd = wv.x * ad.x + wv.y * ad.y + wv.z * ad.z + wv.w * ad.w;
#pragma unroll
    for (int m = 1; m < 64; m <<= 1) {
        ps += __shfl_xor(ps, m);
        pd += __shfl_xor(pd, m);
    }
    if (lane == 0) { e_src[row] = ps; e_dst[row] = pd; }
}

// ---------------- K3: maxdst = max(e_dst) ----------------
__global__ __launch_bounds__(256) void k3_max(const float* __restrict__ e_dst,
                                              float* __restrict__ maxdst) {
    __shared__ float red[4];
    const int t = threadIdx.x;
    float m = -3.4e38f;
    for (int i = t; i < N; i += 256) m = fmaxf(m, e_dst[i]);
#pragma unroll
    for (int msk = 1; msk < 64; msk <<= 1) m = fmaxf(m, __shfl_xor(m, msk));
    if ((t & 63) == 0) red[t >> 6] = m;
    __syncthreads();
    if (t == 0) *maxdst = fmaxf(fmaxf(red[0], red[1]), fmaxf(red[2], red[3]));
}

// ---------------- K4: masked softmax + PV matmul, j-split S-way ----------------
#define BM 64
#define BK 64
#define RB (N / BM)          // 128 row-blocks
#define SPLITS 8             // j-split factor; grid = RB*SPLITS = 1024
#define LDS_STRIDE 72        // ushorts; 144B rows
__global__ __launch_bounds__(512) void k4_main(const float* __restrict__ adj,
                                               const unsigned short* __restrict__ WhT,
                                               const float* __restrict__ e_src,
                                               const float* __restrict__ e_dst,
                                               const float* __restrict__ maxdst,
                                               float* __restrict__ O_part,
                                               float* __restrict__ l_part) {
    __shared__ unsigned short p_lds[BM][LDS_STRIDE];   // P tile bf16 [64][64]
    __shared__ unsigned short wt_lds[D][LDS_STRIDE];   // WhT tile bf16 [256 n][64 k]

    const int t = threadIdx.x;
    const int rb = blockIdx.x & (RB - 1);
    const int s  = blockIdx.x / RB;
    const int r0 = rb * BM;
    const int jbase0 = s * (N / SPLITS);
    const int NIT = (N / SPLITS) / BK;     // 16

    // P-generation coords: one row per 8 threads, 8 cols each
    const int pr = t >> 3;            // 0..63
    const int pc = (t & 7) * 8;       // 0..56
    const int gr = r0 + pr;
    // WhT staging coords: 2 threads per n-row, 32 k each
    const int wn = t >> 1;            // 0..255
    const int wc = (t & 1) * 32;

    const int w = t >> 6;             // wave 0..7 -> cols w*32..w*32+31
    const int lane = t & 63;
    const int quad = lane >> 4, lo = lane & 15;

    const float md = *maxdst;
    const float es = e_src[gr];
    const float m = leaky(es + md);

    f32x4 acc[4][2];
#pragma unroll
    for (int mt = 0; mt < 4; ++mt)
#pragma unroll
        for (int nt = 0; nt < 2; ++nt)
            acc[mt][nt] = (f32x4){0.f, 0.f, 0.f, 0.f};

    float lsum = 0.f;

    // prefetch registers for tile 0
    const float* adj_row = adj + (size_t)gr * N + jbase0 + pc;
    const float* ed_row = e_dst + jbase0 + pc;
    const unsigned short* wt_row = WhT + (size_t)wn * N + jbase0 + wc;
    float4 adjv[2], edv[2];
    uint4 wtv[4];
    adjv[0] = *(const float4*)(adj_row);
    adjv[1] = *(const float4*)(adj_row + 4);
    edv[0] = *(const float4*)(ed_row);
    edv[1] = *(const float4*)(ed_row + 4);
#pragma unroll
    for (int j = 0; j < 4; ++j) wtv[j] = *(const uint4*)(wt_row + j * 8);

    for (int it = 0; it < NIT; ++it) {
        // ---- stage phase: compute P from prefetched regs, write LDS ----
        const int jbase = jbase0 + it * BK + pc;
        float av[8] = {adjv[0].x, adjv[0].y, adjv[0].z, adjv[0].w,
                       adjv[1].x, adjv[1].y, adjv[1].z, adjv[1].w};
        float ev[8] = {edv[0].x, edv[0].y, edv[0].z, edv[0].w,
                       edv[1].x, edv[1].y, edv[1].z, edv[1].w};
        unsigned short pk[8];
#pragma unroll
        for (int jj = 0; jj < 8; ++jj) {
            float e = leaky(es + ev[jj]);
            bool keep = (av[jj] > 0.f) || (jbase + jj == gr);
            float p = keep ? __expf(e - m) : 0.f;
            lsum += p;
            pk[jj] = f2bf(p);
        }
        *(uint4*)&p_lds[pr][pc] = *(uint4*)pk;
#pragma unroll
        for (int j = 0; j < 4; ++j) *(uint4*)&wt_lds[wn][wc + j * 8] = wtv[j];

        // ---- issue next tile's global loads (overlap with MFMA phase) ----
        if (it + 1 < NIT) {
            const int k0 = (it + 1) * BK;
            adjv[0] = *(const float4*)(adj_row + k0);
            adjv[1] = *(const float4*)(adj_row + k0 + 4);
            edv[0] = *(const float4*)(ed_row + k0);
            edv[1] = *(const float4*)(ed_row + k0 + 4);
#pragma unroll
            for (int j = 0; j < 4; ++j) wtv[j] = *(const uint4*)(wt_row + k0 + j * 8);
        }
        __syncthreads();   // LDS tile ready

        // ---- MFMA phase ----
#pragma unroll
        for (int ks = 0; ks < BK; ks += 32) {
            bf16x8 afr[4];
#pragma unroll
            for (int mt = 0; mt < 4; ++mt)
                afr[mt] = *(const bf16x8*)&p_lds[mt * 16 + lo][ks + quad * 8];
#pragma unroll
            for (int nt = 0; nt < 2; ++nt) {
                bf16x8 bfr = *(const bf16x8*)&wt_lds[w * 32 + nt * 16 + lo][ks + quad * 8];
#pragma unroll
                for (int mt = 0; mt < 4; ++mt)
                    acc[mt][nt] = __builtin_amdgcn_mfma_f32_16x16x32_bf16(
                        afr[mt], bfr, acc[mt][nt], 0, 0, 0);
            }
        }
        __syncthreads();   // protect LDS before next stage phase
    }

    // ---- epilogue: reduce per-row partial l (8 threads per row), write partials ----
#pragma unroll
    for (int msk = 1; msk < 8; msk <<= 1) lsum += __shfl_xor(lsum, msk);
    if ((t & 7) == 0) l_part[(size_t)s * N + gr] = lsum;

#pragma unroll
    for (int mt = 0; mt < 4; ++mt) {
#pragma unroll
        for (int nt = 0; nt < 2; ++nt) {
            f32x4 v = acc[mt][nt];
            int col = w * 32 + nt * 16 + lo;
#pragma unroll
            for (int reg = 0; reg < 4; ++reg) {
                int row = mt * 16 + quad * 4 + reg;
                O_part[((size_t)s * N + r0 + row) * D + col] = v[reg];
            }
        }
    }
}

// ---------------- K5: reduce partials, divide by l ----------------
__global__ __launch_bounds__(256) void k5_reduce(const float* __restrict__ O_part,
                                                 const float* __restrict__ l_part,
                                                 float* __restrict__ out) {
    const int r = blockIdx.x;
    const int n = threadIdx.x;
    float lsum = 0.f;
#pragma unroll
    for (int s = 0; s < SPLITS; ++s) lsum += l_part[(size_t)s * N + r];
    float o = 0.f;
#pragma unroll
    for (int s = 0; s < SPLITS; ++s) o += O_part[((size_t)s * N + r) * D + n];
    out[(size_t)r * D + n] = o / lsum;
}

// ---------------- launch ----------------
extern "C" void kernel_launch(void* const* d_in, const int* in_sizes, int n_in,
                              void* d_out, int out_size, void* d_ws, size_t ws_size,
                              hipStream_t stream) {
    const float* x   = (const float*)d_in[0];   // [N, D]
    const float* adj = (const float*)d_in[1];   // [N, N]
    const float* W   = (const float*)d_in[2];   // [D, D]
    const float* a   = (const float*)d_in[3];   // [2*D]
    float* out = (float*)d_out;

    // ws layout (requires ~80.1 MB):
    char* ws = (char*)d_ws;
    float* Wh            = (float*)(ws);                         // 8 MB
    unsigned short* WhT  = (unsigned short*)(ws + 8388608);      // 4 MB
    float* e_src         = (float*)(ws + 12582912);              // 32 KB
    float* e_dst         = (float*)(ws + 12615680);              // 32 KB
    float* maxdst        = (float*)(ws + 12648448);              // 256 B
    float* l_part        = (float*)(ws + 12648704);              // 256 KB (SPLITS*N*4)
    float* O_part        = (float*)(ws + 16777216);              // 64 MB (SPLITS*N*D*4)

    k1_gemm<<<N / K1_BM, 256, 0, stream>>>(x, W, Wh, WhT);
    k2_edot<<<N / 4, 256, 0, stream>>>(Wh, a, e_src, e_dst);
    k3_max<<<1, 256, 0, stream>>>(e_dst, maxdst);
    k4_main<<<RB * SPLITS, 512, 0, stream>>>(adj, WhT, e_src, e_dst, maxdst, O_part, l_part);
    k5_reduce<<<N, 256, 0, stream>>>(O_part, l_part, out);
}

// Round 3
// 482.810 us; speedup vs baseline: 1.5776x; 1.2888x over previous
//
#include <hip/hip_runtime.h>
#include <stdint.h>

#define N 8192
#define D 256

typedef __attribute__((ext_vector_type(4))) float f32x4;
typedef __attribute__((ext_vector_type(8))) short bf16x8;

__device__ __forceinline__ unsigned short f2bf(float f) {
    unsigned u = __float_as_uint(f);
    u += 0x7fff + ((u >> 16) & 1);           // RNE
    return (unsigned short)(u >> 16);
}
__device__ __forceinline__ float leaky(float x) {
    return fmaxf(x, 0.f) + 0.2f * fminf(x, 0.f);
}
// CK-style block_sync_lds: LDS-ordering barrier that does NOT drain vmcnt,
// so register-destination global prefetches stay in flight across it.
__device__ __forceinline__ void sync_lds() {
    asm volatile("s_waitcnt lgkmcnt(0)\n\ts_barrier" ::: "memory");
}

// ---------------- K1: Wh = x @ W (fp32), also write WhT bf16 [D][N] ----------------
#define K1_BM 16
__global__ __launch_bounds__(256) void k1_gemm(const float* __restrict__ x,
                                               const float* __restrict__ W,
                                               float* __restrict__ Wh,
                                               unsigned short* __restrict__ WhT) {
    __shared__ float xsT[32][20];   // [k][r]
    const int t = threadIdx.x;      // = output column
    const int r0 = blockIdx.x * K1_BM;
    float acc[K1_BM];
#pragma unroll
    for (int i = 0; i < K1_BM; ++i) acc[i] = 0.f;

    for (int k0 = 0; k0 < D; k0 += 32) {
        __syncthreads();
        if (t < 128) {
            int r = t >> 3, ks = (t & 7) * 4;
            float4 v = *(const float4*)(x + (size_t)(r0 + r) * D + k0 + ks);
            xsT[ks + 0][r] = v.x; xsT[ks + 1][r] = v.y;
            xsT[ks + 2][r] = v.z; xsT[ks + 3][r] = v.w;
        }
        __syncthreads();
#pragma unroll 8
        for (int kk = 0; kk < 32; ++kk) {
            float wv = W[(size_t)(k0 + kk) * D + t];
#pragma unroll
            for (int rc = 0; rc < K1_BM / 4; ++rc) {
                float4 xv = *(const float4*)&xsT[kk][rc * 4];
                acc[rc * 4 + 0] += xv.x * wv;
                acc[rc * 4 + 1] += xv.y * wv;
                acc[rc * 4 + 2] += xv.z * wv;
                acc[rc * 4 + 3] += xv.w * wv;
            }
        }
    }
#pragma unroll
    for (int r = 0; r < K1_BM; ++r) Wh[(size_t)(r0 + r) * D + t] = acc[r];
    unsigned short pk[K1_BM];
#pragma unroll
    for (int r = 0; r < K1_BM; ++r) pk[r] = f2bf(acc[r]);
    uint4* dst = (uint4*)(WhT + (size_t)t * N + r0);
    dst[0] = *(uint4*)&pk[0];
    dst[1] = *(uint4*)&pk[8];
}

// ---------------- K2: e_src / e_dst (wave per row) ----------------
__global__ __launch_bounds__(256) void k2_edot(const float* __restrict__ Wh,
                                               const float* __restrict__ a,
                                               float* __restrict__ e_src,
                                               float* __restrict__ e_dst) {
    const int wave = threadIdx.x >> 6, lane = threadIdx.x & 63;
    const int row = blockIdx.x * 4 + wave;
    float4 wv = *(const float4*)(Wh + (size_t)row * D + lane * 4);
    float4 as = *(const float4*)(a + lane * 4);
    float4 ad = *(const float4*)(a + D + lane * 4);
    float ps = wv.x * as.x + wv.y * as.y + wv.z * as.z + wv.w * as.w;
    float pd = wv.x * ad.x + wv.y * ad.y + wv.z * ad.z + wv.w * ad.w;
#pragma unroll
    for (int m = 1; m < 64; m <<= 1) {
        ps += __shfl_xor(ps, m);
        pd += __shfl_xor(pd, m);
    }
    if (lane == 0) { e_src[row] = ps; e_dst[row] = pd; }
}

// ---------------- K3: maxdst = max(e_dst) ----------------
__global__ __launch_bounds__(256) void k3_max(const float* __restrict__ e_dst,
                                              float* __restrict__ maxdst) {
    __shared__ float red[4];
    const int t = threadIdx.x;
    float m = -3.4e38f;
    for (int i = t; i < N; i += 256) m = fmaxf(m, e_dst[i]);
#pragma unroll
    for (int msk = 1; msk < 64; msk <<= 1) m = fmaxf(m, __shfl_xor(m, msk));
    if ((t & 63) == 0) red[t >> 6] = m;
    __syncthreads();
    if (t == 0) *maxdst = fmaxf(fmaxf(red[0], red[1]), fmaxf(red[2], red[3]));
}

// ---------------- K4: masked softmax + PV matmul, j-split, 1 raw barrier/iter ----------------
#define BM 64
#define BK 64
#define RB (N / BM)          // 128 row-blocks
#define SPLITS 8             // grid = RB*SPLITS = 1024
#define NITER ((N / SPLITS) / BK)   // 16
#define PSTRIDE 72           // ushorts per P row (144 B)
__global__ __launch_bounds__(512, 4) void k4_main(const float* __restrict__ adj,
                                                  const unsigned short* __restrict__ WhT,
                                                  const float* __restrict__ e_src,
                                                  const float* __restrict__ e_dst,
                                                  const float* __restrict__ maxdst,
                                                  float* __restrict__ O_part,
                                                  float* __restrict__ l_part) {
    __shared__ unsigned short p_lds[2][BM][PSTRIDE];   // double-buffered P tile, 18.4 KB

    const int t = threadIdx.x;
    const int rb = blockIdx.x & (RB - 1);
    const int s  = blockIdx.x >> 7;          // RB = 128
    const int r0 = rb * BM;
    const int j0 = s * (N / SPLITS);

    // P-generation coords: 8 threads per row, 8 cols each
    const int pr = t >> 3;            // 0..63
    const int pc = (t & 7) * 8;       // 0..56
    const int gr = r0 + pr;

    const int w = t >> 6;             // wave 0..7 -> output cols w*32..w*32+31
    const int lane = t & 63;
    const int quad = lane >> 4, lo = lane & 15;

    const float md = *maxdst;
    const float es = e_src[gr];
    const float m = leaky(es + md);

    f32x4 acc[4][2];
#pragma unroll
    for (int mt = 0; mt < 4; ++mt)
#pragma unroll
        for (int nt = 0; nt < 2; ++nt)
            acc[mt][nt] = (f32x4){0.f, 0.f, 0.f, 0.f};
    float lsum = 0.f;

    const float* adj_row = adj + (size_t)gr * N + j0 + pc;
    const float* ed_row  = e_dst + j0 + pc;
    // B-fragment base: row (= Wh col) = w*32 + nt*16 + lo, k offset = quad*8
    const unsigned short* wt_base = WhT + (size_t)(w * 32 + lo) * N + j0 + quad * 8;

    float4 adjv0, adjv1, edv0, edv1;
    bf16x8 bfr[2][2];                 // [ks2][nt], single-buffered (reissued after last use)

    // ---- prologue: loads for tile 0 ----
    adjv0 = *(const float4*)(adj_row);
    adjv1 = *(const float4*)(adj_row + 4);
    edv0  = *(const float4*)(ed_row);
    edv1  = *(const float4*)(ed_row + 4);
#pragma unroll
    for (int ks2 = 0; ks2 < 2; ++ks2)
#pragma unroll
        for (int nt = 0; nt < 2; ++nt)
            bfr[ks2][nt] = *(const bf16x8*)(wt_base + (size_t)nt * (16 * N) + ks2 * 32);

    auto stage = [&](int its, int buf) {
        const int jb = j0 + its * BK + pc;
        float av[8] = {adjv0.x, adjv0.y, adjv0.z, adjv0.w,
                       adjv1.x, adjv1.y, adjv1.z, adjv1.w};
        float ev[8] = {edv0.x, edv0.y, edv0.z, edv0.w,
                       edv1.x, edv1.y, edv1.z, edv1.w};
        unsigned short pk[8];
#pragma unroll
        for (int jj = 0; jj < 8; ++jj) {
            float e = leaky(es + ev[jj]);
            bool keep = (av[jj] > 0.f) || (jb + jj == gr);
            float p = keep ? __expf(e - m) : 0.f;
            lsum += p;
            pk[jj] = f2bf(p);
        }
        *(uint4*)&p_lds[buf][pr][pc] = *(uint4*)pk;
    };

    // stage(0), then prefetch adj/ed for tile 1
    stage(0, 0);
    adjv0 = *(const float4*)(adj_row + BK);
    adjv1 = *(const float4*)(adj_row + BK + 4);
    edv0  = *(const float4*)(ed_row + BK);
    edv1  = *(const float4*)(ed_row + BK + 4);
    sync_lds();

#pragma unroll 2
    for (int it = 0; it < NITER; ++it) {
        const int cb = it & 1, nb = cb ^ 1;

        // ---- MFMA on p_lds[cb] x bfr ----
#pragma unroll
        for (int ks2 = 0; ks2 < 2; ++ks2) {
            bf16x8 afr[4];
#pragma unroll
            for (int mt = 0; mt < 4; ++mt)
                afr[mt] = *(const bf16x8*)&p_lds[cb][mt * 16 + lo][ks2 * 32 + quad * 8];
#pragma unroll
            for (int nt = 0; nt < 2; ++nt)
#pragma unroll
                for (int mt = 0; mt < 4; ++mt)
                    acc[mt][nt] = __builtin_amdgcn_mfma_f32_16x16x32_bf16(
                        afr[mt], bfr[ks2][nt], acc[mt][nt], 0, 0, 0);
        }

        // ---- reissue B-fragment loads for it+1 (WAR-safe: in-order issue) ----
        {
            const int itn = (it + 1 < NITER) ? it + 1 : NITER - 1;
#pragma unroll
            for (int ks2 = 0; ks2 < 2; ++ks2)
#pragma unroll
                for (int nt = 0; nt < 2; ++nt)
                    bfr[ks2][nt] = *(const bf16x8*)(wt_base + (size_t)nt * (16 * N) +
                                                    itn * BK + ks2 * 32);
        }

        // ---- stage(it+1) into p_lds[nb], prefetch adj/ed for it+2 ----
        if (it + 1 < NITER) {
            stage(it + 1, nb);
            const int itn2 = (it + 2 < NITER) ? it + 2 : NITER - 1;
            adjv0 = *(const float4*)(adj_row + itn2 * BK);
            adjv1 = *(const float4*)(adj_row + itn2 * BK + 4);
            edv0  = *(const float4*)(ed_row + itn2 * BK);
            edv1  = *(const float4*)(ed_row + itn2 * BK + 4);
        }
        sync_lds();
    }

    // ---- epilogue: reduce per-row partial l (8 threads per row), write partials ----
#pragma unroll
    for (int msk = 1; msk < 8; msk <<= 1) lsum += __shfl_xor(lsum, msk);
    if ((t & 7) == 0) l_part[(size_t)s * N + gr] = lsum;

#pragma unroll
    for (int mt = 0; mt < 4; ++mt) {
#pragma unroll
        for (int nt = 0; nt < 2; ++nt) {
            f32x4 v = acc[mt][nt];
            int col = w * 32 + nt * 16 + lo;
#pragma unroll
            for (int reg = 0; reg < 4; ++reg) {
                int row = mt * 16 + quad * 4 + reg;
                O_part[((size_t)s * N + r0 + row) * D + col] = v[reg];
            }
        }
    }
}

// ---------------- K5: reduce partials (float4), divide by l ----------------
__global__ __launch_bounds__(256) void k5_reduce(const float* __restrict__ O_part,
                                                 const float* __restrict__ l_part,
                                                 float* __restrict__ out) {
    const int idx = blockIdx.x * 256 + threadIdx.x;   // over N*D/4
    const int r = idx >> 6;                           // D/4 = 64 float4 per row
    float lsum = 0.f;
#pragma unroll
    for (int s = 0; s < SPLITS; ++s) lsum += l_part[(size_t)s * N + r];
    f32x4 o = (f32x4){0.f, 0.f, 0.f, 0.f};
#pragma unroll
    for (int s = 0; s < SPLITS; ++s)
        o += *(const f32x4*)(O_part + (size_t)s * N * D + (size_t)idx * 4);
    const float inv = 1.f / lsum;
    *(f32x4*)(out + (size_t)idx * 4) = o * inv;
}

// ---------------- launch ----------------
extern "C" void kernel_launch(void* const* d_in, const int* in_sizes, int n_in,
                              void* d_out, int out_size, void* d_ws, size_t ws_size,
                              hipStream_t stream) {
    const float* x   = (const float*)d_in[0];   // [N, D]
    const float* adj = (const float*)d_in[1];   // [N, N]
    const float* W   = (const float*)d_in[2];   // [D, D]
    const float* a   = (const float*)d_in[3];   // [2*D]
    float* out = (float*)d_out;

    // ws layout (~80.1 MB):
    char* ws = (char*)d_ws;
    float* Wh            = (float*)(ws);                         // 8 MB
    unsigned short* WhT  = (unsigned short*)(ws + 8388608);      // 4 MB
    float* e_src         = (float*)(ws + 12582912);              // 32 KB
    float* e_dst         = (float*)(ws + 12615680);              // 32 KB
    float* maxdst        = (float*)(ws + 12648448);              // 256 B
    float* l_part        = (float*)(ws + 12648704);              // 256 KB (SPLITS*N*4)
    float* O_part        = (float*)(ws + 16777216);              // 64 MB (SPLITS*N*D*4)

    k1_gemm<<<N / K1_BM, 256, 0, stream>>>(x, W, Wh, WhT);
    k2_edot<<<N / 4, 256, 0, stream>>>(Wh, a, e_src, e_dst);
    k3_max<<<1, 256, 0, stream>>>(e_dst, maxdst);
    k4_main<<<RB * SPLITS, 512, 0, stream>>>(adj, WhT, e_src, e_dst, maxdst, O_part, l_part);
    k5_reduce<<<N * D / 4 / 256, 256, 0, stream>>>(O_part, l_part, out);
}